// Round 2
// baseline (425.105 us; speedup 1.0000x reference)
//
#include <hip/hip_runtime.h>
#include <hip/hip_bf16.h>
#include <cstdint>
#include <cstddef>

#define B_ROWS 8192
#define N_COLS 4096
#define P_BLK 8
#define D_BLK 512
#define EPSV 1e-5f

typedef __bf16 bf16x8 __attribute__((ext_vector_type(8)));
typedef float f32x4 __attribute__((ext_vector_type(4)));

// ---------------------------------------------------------------------------
// async 16B global -> LDS (HW: LDS dst = wave-uniform base + lane*16)
// ---------------------------------------------------------------------------
__device__ __forceinline__ void async_ld16(const void* g, void* l) {
    __builtin_amdgcn_global_load_lds(
        (const __attribute__((address_space(1))) void*)g,
        (__attribute__((address_space(3))) void*)l,
        16, 0, 0);
}

// ---------------------------------------------------------------------------
// x fp32 -> bf16 (blocks [0,16384)) fused with W1 transpose (blocks >= 16384)
// ---------------------------------------------------------------------------
__global__ __launch_bounds__(256) void prep_k(const float* __restrict__ x,
                                              __hip_bfloat16* __restrict__ xb,
                                              const float* __restrict__ W1,
                                              __hip_bfloat16* __restrict__ w1t) {
    __shared__ float tl[32][33];
    if (blockIdx.x < 16384) {
        size_t i = ((size_t)blockIdx.x * 256 + threadIdx.x) * 8;
        float4 v0 = *(const float4*)(x + i);
        float4 v1 = *(const float4*)(x + i + 4);
        union { __hip_bfloat16 h[8]; uint4 u; } r;
        r.h[0] = __float2bfloat16(v0.x); r.h[1] = __float2bfloat16(v0.y);
        r.h[2] = __float2bfloat16(v0.z); r.h[3] = __float2bfloat16(v0.w);
        r.h[4] = __float2bfloat16(v1.x); r.h[5] = __float2bfloat16(v1.y);
        r.h[6] = __float2bfloat16(v1.z); r.h[7] = __float2bfloat16(v1.w);
        *(uint4*)(xb + i) = r.u;
        return;
    }
    const int n = blockIdx.x - 16384;            // 0..2047
    const int p = n >> 8;
    const int rem = n & 255;
    const int d0 = (rem & 15) * 32, e0 = (rem >> 4) * 32;
    const int tx = threadIdx.x & 31, ty = threadIdx.x >> 5;
    const float* Wp = W1 + (size_t)p * D_BLK * D_BLK;
    for (int j = 0; j < 32; j += 8) {
        int d = d0 + ty + j;
        tl[ty + j][tx] = Wp[(size_t)d * D_BLK + e0 + tx];
    }
    __syncthreads();
    __hip_bfloat16* Wtp = w1t + (size_t)p * D_BLK * D_BLK;
    for (int j = 0; j < 32; j += 8) {
        int e = e0 + ty + j;
        Wtp[(size_t)e * D_BLK + d0 + tx] = __float2bfloat16(tl[tx][ty + j]);
    }
}

// ---------------------------------------------------------------------------
// mid kernel: blocks [0,2048): W2' = a[d]*W2 transposed bf16 (a from stats);
//             blocks [2048,2176): bias2'[col] = bias2 + sum_d c[d]*W2[p,d,e]
//             (c from stats), 8-way d-chunk parallel, atomic accumulate.
// finalize_k folded in: a,c computed inline from sums/sumsq.
// ---------------------------------------------------------------------------
__global__ __launch_bounds__(256) void mid_k(const float* __restrict__ W2,
                                             const float* __restrict__ sums,
                                             const float* __restrict__ sumsq,
                                             const float* __restrict__ bnw,
                                             const float* __restrict__ bnb,
                                             const float* __restrict__ bias2,
                                             __hip_bfloat16* __restrict__ w2t,
                                             float* __restrict__ b2p) {
    __shared__ float tl[32][33];
    __shared__ float as_[32];
    const float invB = 1.0f / B_ROWS;
    if (blockIdx.x < 2048) {
        const int n = blockIdx.x;
        const int p = n >> 8;
        const int rem = n & 255;
        const int d0 = (rem & 15) * 32, e0 = (rem >> 4) * 32;
        const int tx = threadIdx.x & 31, ty = threadIdx.x >> 5;
        if (threadIdx.x < 32) {
            int idx = p * D_BLK + d0 + threadIdx.x;
            float m = sums[idx] * invB;
            float var = sumsq[idx] * invB - m * m;
            as_[threadIdx.x] = bnw[idx] * rsqrtf(var + EPSV);
        }
        __syncthreads();
        const float* Wp = W2 + (size_t)p * D_BLK * D_BLK;
        for (int j = 0; j < 32; j += 8) {
            int d = d0 + ty + j;
            tl[ty + j][tx] = Wp[(size_t)d * D_BLK + e0 + tx] * as_[ty + j];
        }
        __syncthreads();
        __hip_bfloat16* Wtp = w2t + (size_t)p * D_BLK * D_BLK;
        for (int j = 0; j < 32; j += 8) {
            int e = e0 + ty + j;
            Wtp[(size_t)e * D_BLK + d0 + tx] = __float2bfloat16(tl[tx][ty + j]);
        }
        return;
    }
    const int n2 = blockIdx.x - 2048;            // 0..127
    const int colblk = n2 & 15, chunk = n2 >> 4;
    const int col = colblk * 256 + threadIdx.x;
    const int p = col >> 9;
    const int e = col & (D_BLK - 1);
    const int d0 = chunk * 64;
    float acc = (chunk == 0) ? bias2[col] : 0.0f;
    for (int d = 0; d < 64; d++) {
        int idx = p * D_BLK + d0 + d;
        float m = sums[idx] * invB;
        float var = sumsq[idx] * invB - m * m;
        float ai = bnw[idx] * rsqrtf(var + EPSV);
        float ci = bnb[idx] - m * ai;
        acc += ci * W2[((size_t)p * D_BLK + d0 + d) * D_BLK + e];
    }
    atomicAdd(&b2p[col], acc);
}

// ---------------------------------------------------------------------------
// GEMM core: 256x256 tile, BK=64, 8 waves (2M x 4N), 512 threads, 128 KiB
// dynamic LDS, 8-phase counted-vmcnt schedule (T3+T4) + setprio (T5).
//
// LDS: ldsA[2 buf][2 half][128 rows][64 k] bf16 (64 KiB), ldsB same (64 KiB).
// Swizzle (T2): within a 128 B row, 16B-slot holding col-bytes c is
// c ^ ((row&7)<<4). Realized on the *source* global address (gload_lds dst
// is linear) and applied identically on the ds_read side (involution).
// -> each ds_read_b128: 8 lanes per 16B bank-slot = optimal (1024B / 128B/clk).
//
// Schedule per iteration it (tiles E=2it->buf0, O=2it+1->buf1):
//  ph0: ds A(i0-3,E)+B(j0-1,E) | stage B1(O)        | 16 MFMA Q(M03,N01)
//  ph1: ds B(j2-3,E)           | stage A1(O)        | Q(M03,N23)
//  ph2: ds A(i4-7,E)           | stage B0(E+2)      | Q(M47,N23)
//  ph3: -                      | stage A0(E+2) vmcnt(4) | Q(M47,N01)
//  ph4-7: same pattern on O, staging B1/A1(E+2), B0/A0(O+2), vmcnt(4) @ ph7.
// vmcnt(4) retires exactly the next tile's 4 half-tiles (8 loads), leaving
// the 2 just-issued half-tiles (4 loads) in flight. Write-after-read: each
// stage targets a half last read >=1 end-barrier earlier (verified per phase).
// Tail it=3: stages of tiles 8/9 skipped; ph3 drains vmcnt(0); ph7 no wait.
// ---------------------------------------------------------------------------
__device__ __forceinline__ void gemm_core256(const __hip_bfloat16* __restrict__ A,
                                             const __hip_bfloat16* __restrict__ Bt,
                                             int row_base, int col_base,
                                             f32x4 acc[8][4]) {
    extern __shared__ __align__(16) __hip_bfloat16 lds[];
    __hip_bfloat16* ldsA = lds;             // [2][2][8192]
    __hip_bfloat16* ldsB = lds + 32768;     // [2][2][8192]

    const int tid = threadIdx.x;
    const int lane = tid & 63;
    const int w = tid >> 6;
    const int p = col_base >> 9;
    const int ebase = col_base & (D_BLK - 1);

    // staging map: thread tid owns 16B chunks q=tid (rows 0-63 of half) and
    // q=tid+512 (rows 64-127). row r1=tid>>3, src col = ((tid&7)^(r1&7))<<4 B.
    const int r1 = tid >> 3;
    const int ce = ((((tid >> 3) ^ tid) & 7) << 3);   // element offset
    const __hip_bfloat16* aBase = A + (size_t)(row_base + r1) * N_COLS + p * D_BLK + ce;
    const __hip_bfloat16* bBase = Bt + (size_t)(p * D_BLK + ebase + r1) * D_BLK + ce;
    __hip_bfloat16* dA = ldsA + tid * 8;
    __hip_bfloat16* dB = ldsB + tid * 8;

#define STAGE_A(buf, half, kt) do { \
        const __hip_bfloat16* g_ = aBase + (size_t)(half) * 128 * N_COLS + (kt) * 64; \
        __hip_bfloat16* d_ = dA + ((buf) * 2 + (half)) * 8192; \
        async_ld16(g_, d_); \
        async_ld16(g_ + (size_t)64 * N_COLS, d_ + 4096); } while (0)
#define STAGE_B(buf, half, kt) do { \
        const __hip_bfloat16* g_ = bBase + (size_t)(half) * 128 * D_BLK + (kt) * 64; \
        __hip_bfloat16* d_ = dB + ((buf) * 2 + (half)) * 8192; \
        async_ld16(g_, d_); \
        async_ld16(g_ + (size_t)64 * D_BLK, d_ + 4096); } while (0)

    // fragment map: row lr = i*16+fm, byte col (kk*64 + kq*16) ^ ((fm&7)<<4)
    const int fm = lane & 15;
    const int kq = lane >> 4;
    const int f0 = ((kq * 16) ^ ((fm & 7) << 4)) >> 1;
    const int f1 = ((64 + kq * 16) ^ ((fm & 7) << 4)) >> 1;
    const int ha = w >> 2;            // wave's A half (wm>>7)
    const int hb = (w >> 1) & 1;      // wave's B half
    const int lcb = (w & 1) * 64;     // B local col base within half

#define LDA(buf, i, kk) (*(const bf16x8*)(ldsA + (buf) * 16384 + ha * 8192 + \
        (((i) * 16 + fm) * 64) + ((kk) ? f1 : f0)))
#define LDB(buf, j, kk) (*(const bf16x8*)(ldsB + (buf) * 16384 + hb * 8192 + \
        ((lcb + (j) * 16 + fm) * 64) + ((kk) ? f1 : f0)))

#define PHASE_TOP() do { __builtin_amdgcn_s_barrier(); \
        asm volatile("s_waitcnt lgkmcnt(0)" ::: "memory"); \
        __builtin_amdgcn_sched_barrier(0); \
        __builtin_amdgcn_s_setprio(1); } while (0)
#define PHASE_BOT() do { __builtin_amdgcn_s_setprio(0); \
        __builtin_amdgcn_s_barrier(); \
        asm volatile("" ::: "memory"); } while (0)

#pragma unroll
    for (int i = 0; i < 8; i++)
#pragma unroll
        for (int j = 0; j < 4; j++)
            acc[i][j] = (f32x4){0.0f, 0.0f, 0.0f, 0.0f};

    // prologue: tile0 all 4 halves + tile1 B0,A0 (12 loads). vmcnt(4)
    // retires tile0's 8, leaving tile1's 4 in flight (steady-state entry).
    STAGE_B(0, 0, 0); STAGE_A(0, 0, 0); STAGE_B(0, 1, 0); STAGE_A(0, 1, 0);
    STAGE_B(1, 0, 1); STAGE_A(1, 0, 1);
    asm volatile("s_waitcnt vmcnt(4)" ::: "memory");
    __builtin_amdgcn_s_barrier();
    asm volatile("" ::: "memory");

#pragma unroll
    for (int it = 0; it < 4; ++it) {
        const int kO = 2 * it + 1, kE2 = 2 * it + 2, kO2 = 2 * it + 3;
        const bool last = (it == 3);
        bf16x8 ar[4][2], b0[2][2], b1[2][2];

        // ---- ph0 (tile E, buf0): Q(M0-3 x N0-1)
#pragma unroll
        for (int i = 0; i < 4; i++) { ar[i][0] = LDA(0, i, 0); ar[i][1] = LDA(0, i, 1); }
#pragma unroll
        for (int j = 0; j < 2; j++) { b0[j][0] = LDB(0, j, 0); b0[j][1] = LDB(0, j, 1); }
        STAGE_B(1, 1, kO);
        PHASE_TOP();
#pragma unroll
        for (int i = 0; i < 4; i++)
#pragma unroll
            for (int j = 0; j < 2; j++)
#pragma unroll
                for (int kk = 0; kk < 2; kk++)
                    acc[i][j] = __builtin_amdgcn_mfma_f32_16x16x32_bf16(
                        ar[i][kk], b0[j][kk], acc[i][j], 0, 0, 0);
        PHASE_BOT();

        // ---- ph1: Q(M0-3 x N2-3)
#pragma unroll
        for (int j = 0; j < 2; j++) { b1[j][0] = LDB(0, j + 2, 0); b1[j][1] = LDB(0, j + 2, 1); }
        STAGE_A(1, 1, kO);
        PHASE_TOP();
#pragma unroll
        for (int i = 0; i < 4; i++)
#pragma unroll
            for (int j = 0; j < 2; j++)
#pragma unroll
                for (int kk = 0; kk < 2; kk++)
                    acc[i][j + 2] = __builtin_amdgcn_mfma_f32_16x16x32_bf16(
                        ar[i][kk], b1[j][kk], acc[i][j + 2], 0, 0, 0);
        PHASE_BOT();

        // ---- ph2: Q(M4-7 x N2-3)
#pragma unroll
        for (int i = 0; i < 4; i++) { ar[i][0] = LDA(0, i + 4, 0); ar[i][1] = LDA(0, i + 4, 1); }
        if (!last) STAGE_B(0, 0, kE2);
        PHASE_TOP();
#pragma unroll
        for (int i = 0; i < 4; i++)
#pragma unroll
            for (int j = 0; j < 2; j++)
#pragma unroll
                for (int kk = 0; kk < 2; kk++)
                    acc[i + 4][j + 2] = __builtin_amdgcn_mfma_f32_16x16x32_bf16(
                        ar[i][kk], b1[j][kk], acc[i + 4][j + 2], 0, 0, 0);
        PHASE_BOT();

        // ---- ph3: Q(M4-7 x N0-1); wait for tile O complete
        if (!last) {
            STAGE_A(0, 0, kE2);
            asm volatile("s_waitcnt vmcnt(4)" ::: "memory");
        } else {
            asm volatile("s_waitcnt vmcnt(0)" ::: "memory");
        }
        PHASE_TOP();
#pragma unroll
        for (int i = 0; i < 4; i++)
#pragma unroll
            for (int j = 0; j < 2; j++)
#pragma unroll
                for (int kk = 0; kk < 2; kk++)
                    acc[i + 4][j] = __builtin_amdgcn_mfma_f32_16x16x32_bf16(
                        ar[i][kk], b0[j][kk], acc[i + 4][j], 0, 0, 0);
        PHASE_BOT();

        // ---- ph4 (tile O, buf1): Q(M0-3 x N0-1)
#pragma unroll
        for (int i = 0; i < 4; i++) { ar[i][0] = LDA(1, i, 0); ar[i][1] = LDA(1, i, 1); }
#pragma unroll
        for (int j = 0; j < 2; j++) { b0[j][0] = LDB(1, j, 0); b0[j][1] = LDB(1, j, 1); }
        if (!last) STAGE_B(0, 1, kE2);
        PHASE_TOP();
#pragma unroll
        for (int i = 0; i < 4; i++)
#pragma unroll
            for (int j = 0; j < 2; j++)
#pragma unroll
                for (int kk = 0; kk < 2; kk++)
                    acc[i][j] = __builtin_amdgcn_mfma_f32_16x16x32_bf16(
                        ar[i][kk], b0[j][kk], acc[i][j], 0, 0, 0);
        PHASE_BOT();

        // ---- ph5: Q(M0-3 x N2-3)
#pragma unroll
        for (int j = 0; j < 2; j++) { b1[j][0] = LDB(1, j + 2, 0); b1[j][1] = LDB(1, j + 2, 1); }
        if (!last) STAGE_A(0, 1, kE2);
        PHASE_TOP();
#pragma unroll
        for (int i = 0; i < 4; i++)
#pragma unroll
            for (int j = 0; j < 2; j++)
#pragma unroll
                for (int kk = 0; kk < 2; kk++)
                    acc[i][j + 2] = __builtin_amdgcn_mfma_f32_16x16x32_bf16(
                        ar[i][kk], b1[j][kk], acc[i][j + 2], 0, 0, 0);
        PHASE_BOT();

        // ---- ph6: Q(M4-7 x N2-3)
#pragma unroll
        for (int i = 0; i < 4; i++) { ar[i][0] = LDA(1, i + 4, 0); ar[i][1] = LDA(1, i + 4, 1); }
        if (!last) STAGE_B(1, 0, kO2);
        PHASE_TOP();
#pragma unroll
        for (int i = 0; i < 4; i++)
#pragma unroll
            for (int j = 0; j < 2; j++)
#pragma unroll
                for (int kk = 0; kk < 2; kk++)
                    acc[i + 4][j + 2] = __builtin_amdgcn_mfma_f32_16x16x32_bf16(
                        ar[i][kk], b1[j][kk], acc[i + 4][j + 2], 0, 0, 0);
        PHASE_BOT();

        // ---- ph7: Q(M4-7 x N0-1); wait for tile E+2 complete
        if (!last) {
            STAGE_A(1, 0, kO2);
            asm volatile("s_waitcnt vmcnt(4)" ::: "memory");
        }
        PHASE_TOP();
#pragma unroll
        for (int i = 0; i < 4; i++)
#pragma unroll
            for (int j = 0; j < 2; j++)
#pragma unroll
                for (int kk = 0; kk < 2; kk++)
                    acc[i + 4][j] = __builtin_amdgcn_mfma_f32_16x16x32_bf16(
                        ar[i][kk], b0[j][kk], acc[i + 4][j], 0, 0, 0);
        PHASE_BOT();
    }
#undef STAGE_A
#undef STAGE_B
#undef LDA
#undef LDB
#undef PHASE_TOP
#undef PHASE_BOT
}

// ---------------------------------------------------------------------------
// block swizzle: 512 blocks, b%8 = p (XCD round-robin -> XCD k owns p==k);
// within XCD: m = b>>3, row_tile = m>>1, col_tile = (p<<1)|(m&1) -> the two
// col-tiles of a p share their 256-row A-slab back-to-back (L2 hit).
// ---------------------------------------------------------------------------
__device__ __forceinline__ void decode_tile256(int n, int& row_base, int& col_base) {
    const int p = n & 7;
    const int m = n >> 3;
    row_base = (m >> 1) * 256;
    col_base = (((p << 1) | (m & 1))) * 256;
}

// ---------------------------------------------------------------------------
// GEMM1: h = x @ W1 + bias1 (bf16 out), plus per-column sum / sumsq atomics
// ---------------------------------------------------------------------------
__global__ __launch_bounds__(512, 2) void gemm1_k(const __hip_bfloat16* __restrict__ xb,
                                                  const __hip_bfloat16* __restrict__ w1t,
                                                  const float* __restrict__ bias1,
                                                  __hip_bfloat16* __restrict__ h,
                                                  float* __restrict__ sum,
                                                  float* __restrict__ sumsq) {
    int row_base, col_base;
    decode_tile256(blockIdx.x, row_base, col_base);

    f32x4 acc[8][4];
    gemm_core256(xb, w1t, row_base, col_base, acc);

    const int tid = threadIdx.x;
    const int lane = tid & 63;
    const int w = tid >> 6;
    const int wm = (w >> 2) * 128;
    const int wn = (w & 3) * 64;
    const int cr = (lane >> 4) * 4;   // C/D: row = quad*4 + reg
    const int cc = lane & 15;         // C/D: col = lane&15

#pragma unroll
    for (int j = 0; j < 4; j++) {
        const int col = col_base + wn + j * 16 + cc;
        const float b1 = bias1[col];
        float s = 0.0f, sq = 0.0f;
#pragma unroll
        for (int i = 0; i < 8; i++) {
            const int row0 = row_base + wm + i * 16 + cr;
#pragma unroll
            for (int r = 0; r < 4; r++) {
                float v = acc[i][j][r] + b1;
                h[(size_t)(row0 + r) * N_COLS + col] = __float2bfloat16(v);
                s += v;
                sq += v * v;
            }
        }
        s  += __shfl_xor(s, 16);  s  += __shfl_xor(s, 32);
        sq += __shfl_xor(sq, 16); sq += __shfl_xor(sq, 32);
        if (lane < 16) {
            atomicAdd(&sum[col], s);
            atomicAdd(&sumsq[col], sq);
        }
    }
}

// ---------------------------------------------------------------------------
// GEMM2: o3 = h_bf16 @ W2' + bias2' + x ; out = (g + sig(be*o3)*(1-g)) * o3
// ---------------------------------------------------------------------------
__global__ __launch_bounds__(512, 2) void gemm2_k(const __hip_bfloat16* __restrict__ h,
                                                  const __hip_bfloat16* __restrict__ w2t,
                                                  const float* __restrict__ bias2p,
                                                  const __hip_bfloat16* __restrict__ xb,
                                                  const float* __restrict__ gamma3,
                                                  const float* __restrict__ beta3,
                                                  float* __restrict__ out) {
    int row_base, col_base;
    decode_tile256(blockIdx.x, row_base, col_base);

    f32x4 acc[8][4];
    gemm_core256(h, w2t, row_base, col_base, acc);

    const int tid = threadIdx.x;
    const int lane = tid & 63;
    const int w = tid >> 6;
    const int wm = (w >> 2) * 128;
    const int wn = (w & 3) * 64;
    const int cr = (lane >> 4) * 4;
    const int cc = lane & 15;

#pragma unroll
    for (int j = 0; j < 4; j++) {
        const int col = col_base + wn + j * 16 + cc;
        const float bb = bias2p[col];
        const float g  = gamma3[col];
        const float be = beta3[col];
#pragma unroll
        for (int i = 0; i < 8; i++) {
            const int row0 = row_base + wm + i * 16 + cr;
#pragma unroll
            for (int r = 0; r < 4; r++) {
                const size_t idx = (size_t)(row0 + r) * N_COLS + col;
                float o3 = acc[i][j][r] + bb + __bfloat162float(xb[idx]);
                float sg = __fdividef(1.0f, 1.0f + __expf(-be * o3));
                out[idx] = (g + sg * (1.0f - g)) * o3;
            }
        }
    }
}

// ---------------------------------------------------------------------------
extern "C" void kernel_launch(void* const* d_in, const int* in_sizes, int n_in,
                              void* d_out, int out_size, void* d_ws, size_t ws_size,
                              hipStream_t stream) {
    const float* x     = (const float*)d_in[0];
    const float* W1    = (const float*)d_in[1];
    const float* bias1 = (const float*)d_in[2];
    const float* W2    = (const float*)d_in[3];
    const float* bias2 = (const float*)d_in[4];
    const float* bnw   = (const float*)d_in[5];
    const float* bnb   = (const float*)d_in[6];
    const float* gam3  = (const float*)d_in[7];
    const float* bet3  = (const float*)d_in[8];
    float* out = (float*)d_out;

    // workspace layout
    char* ws = (char*)d_ws;
    const size_t XB_BYTES = (size_t)B_ROWS * N_COLS * 2;        // 64 MiB
    const size_t H_BYTES  = (size_t)B_ROWS * N_COLS * 2;        // 64 MiB
    const size_t WT_BYTES = (size_t)P_BLK * D_BLK * D_BLK * 2;  // 4 MiB
    const size_t V_BYTES  = (size_t)N_COLS * 4;                 // 16 KiB

    __hip_bfloat16* xb   = (__hip_bfloat16*)(ws);
    __hip_bfloat16* hbuf = (__hip_bfloat16*)(ws + XB_BYTES);
    __hip_bfloat16* w1t  = (__hip_bfloat16*)(ws + XB_BYTES + H_BYTES);
    __hip_bfloat16* w2t  = (__hip_bfloat16*)(ws + XB_BYTES + H_BYTES + WT_BYTES);
    float* sums  = (float*)(ws + XB_BYTES + H_BYTES + 2 * WT_BYTES);
    float* sumsq = sums + N_COLS;
    float* b2p   = sums + 2 * N_COLS;   // zeroed: mid_k accumulates via atomics

    (void)in_sizes; (void)n_in; (void)out_size; (void)ws_size;

    // allow 128 KiB dynamic LDS for the GEMMs (idempotent; not a stream op)
    static int attr_set = 0;
    if (!attr_set) {
        hipFuncSetAttribute((const void*)gemm1_k,
                            hipFuncAttributeMaxDynamicSharedMemorySize, 131072);
        hipFuncSetAttribute((const void*)gemm2_k,
                            hipFuncAttributeMaxDynamicSharedMemorySize, 131072);
        attr_set = 1;
    }

    // zero stats accumulators + bias2' (ws is poisoned before every call)
    hipMemsetAsync(sums, 0, 3 * V_BYTES, stream);

    // x -> bf16  fused with  W1 -> bf16 transposed [p,e,d]
    prep_k<<<dim3(16384 + 2048), dim3(256), 0, stream>>>(x, xb, W1, w1t);
    // GEMM1 + bias + stats (256^2 tile, 8-phase)
    gemm1_k<<<dim3((B_ROWS / 256) * (N_COLS / 256)), dim3(512), 131072, stream>>>(
        xb, w1t, bias1, hbuf, sums, sumsq);
    // W2' (scale from stats, inline finalize) + bias2' (inline c)
    mid_k<<<dim3(2048 + 128), dim3(256), 0, stream>>>(
        W2, sums, sumsq, bnw, bnb, bias2, w2t, b2p);
    // GEMM2 + residual + gate (256^2 tile, 8-phase)
    gemm2_k<<<dim3((B_ROWS / 256) * (N_COLS / 256)), dim3(512), 131072, stream>>>(
        hbuf, w2t, b2p, xb, gam3, bet3, out);
}

// Round 3
// 413.512 us; speedup vs baseline: 1.0280x; 1.0280x over previous
//
#include <hip/hip_runtime.h>
#include <hip/hip_bf16.h>
#include <cstdint>
#include <cstddef>

#define B_ROWS 8192
#define N_COLS 4096
#define P_BLK 8
#define D_BLK 512
#define EPSV 1e-5f

typedef __bf16 bf16x8 __attribute__((ext_vector_type(8)));
typedef float f32x4 __attribute__((ext_vector_type(4)));

// ---------------------------------------------------------------------------
// async 16B global -> LDS (HW: LDS dst = wave-uniform base + lane*16)
// ---------------------------------------------------------------------------
__device__ __forceinline__ void async_ld16(const void* g, void* l) {
    __builtin_amdgcn_global_load_lds(
        (const __attribute__((address_space(1))) void*)g,
        (__attribute__((address_space(3))) void*)l,
        16, 0, 0);
}

// ---------------------------------------------------------------------------
// block swizzle: flat id n -> (row_tile, col_tile) such that the 4 blocks
// sharing one A-slab (same row-strip, same diagonal block p) are n, n+8,
// n+16, n+24 -> same XCD under %8 round-robin.
// ---------------------------------------------------------------------------
__device__ __forceinline__ void decode_tile(int n, int& row_base, int& col_base) {
    const int row_tile = n >> 5;
    const int col_tile = ((n & 7) << 2) | ((n >> 3) & 3);
    row_base = row_tile * 128;
    col_base = col_tile * 128;
}

// ---------------------------------------------------------------------------
// x fp32 -> bf16 (blocks [0,16384)) fused with W1 transpose (blocks >= 16384)
// ---------------------------------------------------------------------------
__global__ __launch_bounds__(256) void prep_k(const float* __restrict__ x,
                                              __hip_bfloat16* __restrict__ xb,
                                              const float* __restrict__ W1,
                                              __hip_bfloat16* __restrict__ w1t) {
    __shared__ float tl[32][33];
    if (blockIdx.x < 16384) {
        size_t i = ((size_t)blockIdx.x * 256 + threadIdx.x) * 8;
        float4 v0 = *(const float4*)(x + i);
        float4 v1 = *(const float4*)(x + i + 4);
        union { __hip_bfloat16 h[8]; uint4 u; } r;
        r.h[0] = __float2bfloat16(v0.x); r.h[1] = __float2bfloat16(v0.y);
        r.h[2] = __float2bfloat16(v0.z); r.h[3] = __float2bfloat16(v0.w);
        r.h[4] = __float2bfloat16(v1.x); r.h[5] = __float2bfloat16(v1.y);
        r.h[6] = __float2bfloat16(v1.z); r.h[7] = __float2bfloat16(v1.w);
        *(uint4*)(xb + i) = r.u;
        return;
    }
    const int n = blockIdx.x - 16384;            // 0..2047
    const int p = n >> 8;
    const int rem = n & 255;
    const int d0 = (rem & 15) * 32, e0 = (rem >> 4) * 32;
    const int tx = threadIdx.x & 31, ty = threadIdx.x >> 5;
    const float* Wp = W1 + (size_t)p * D_BLK * D_BLK;
    for (int j = 0; j < 32; j += 8) {
        int d = d0 + ty + j;
        tl[ty + j][tx] = Wp[(size_t)d * D_BLK + e0 + tx];
    }
    __syncthreads();
    __hip_bfloat16* Wtp = w1t + (size_t)p * D_BLK * D_BLK;
    for (int j = 0; j < 32; j += 8) {
        int e = e0 + ty + j;
        Wtp[(size_t)e * D_BLK + d0 + tx] = __float2bfloat16(tl[tx][ty + j]);
    }
}

// ---------------------------------------------------------------------------
// mid kernel: blocks [0,2048): W2' = a[d]*W2 transposed bf16 (a from stats);
//             blocks [2048,2176): bias2'[col] += bias2 + sum_d c[d]*W2[p,d,e]
// finalize_k folded in: a,c computed inline from sums/sumsq.
// ---------------------------------------------------------------------------
__global__ __launch_bounds__(256) void mid_k(const float* __restrict__ W2,
                                             const float* __restrict__ sums,
                                             const float* __restrict__ sumsq,
                                             const float* __restrict__ bnw,
                                             const float* __restrict__ bnb,
                                             const float* __restrict__ bias2,
                                             __hip_bfloat16* __restrict__ w2t,
                                             float* __restrict__ b2p) {
    __shared__ float tl[32][33];
    __shared__ float as_[32];
    const float invB = 1.0f / B_ROWS;
    if (blockIdx.x < 2048) {
        const int n = blockIdx.x;
        const int p = n >> 8;
        const int rem = n & 255;
        const int d0 = (rem & 15) * 32, e0 = (rem >> 4) * 32;
        const int tx = threadIdx.x & 31, ty = threadIdx.x >> 5;
        if (threadIdx.x < 32) {
            int idx = p * D_BLK + d0 + threadIdx.x;
            float m = sums[idx] * invB;
            float var = sumsq[idx] * invB - m * m;
            as_[threadIdx.x] = bnw[idx] * rsqrtf(var + EPSV);
        }
        __syncthreads();
        const float* Wp = W2 + (size_t)p * D_BLK * D_BLK;
        for (int j = 0; j < 32; j += 8) {
            int d = d0 + ty + j;
            tl[ty + j][tx] = Wp[(size_t)d * D_BLK + e0 + tx] * as_[ty + j];
        }
        __syncthreads();
        __hip_bfloat16* Wtp = w2t + (size_t)p * D_BLK * D_BLK;
        for (int j = 0; j < 32; j += 8) {
            int e = e0 + ty + j;
            Wtp[(size_t)e * D_BLK + d0 + tx] = __float2bfloat16(tl[tx][ty + j]);
        }
        return;
    }
    const int n2 = blockIdx.x - 2048;            // 0..127
    const int colblk = n2 & 15, chunk = n2 >> 4;
    const int col = colblk * 256 + threadIdx.x;
    const int p = col >> 9;
    const int e = col & (D_BLK - 1);
    const int d0 = chunk * 64;
    float acc = (chunk == 0) ? bias2[col] : 0.0f;
    for (int d = 0; d < 64; d++) {
        int idx = p * D_BLK + d0 + d;
        float m = sums[idx] * invB;
        float var = sumsq[idx] * invB - m * m;
        float ai = bnw[idx] * rsqrtf(var + EPSV);
        float ci = bnb[idx] - m * ai;
        acc += ci * W2[((size_t)p * D_BLK + d0 + d) * D_BLK + e];
    }
    atomicAdd(&b2p[col], acc);
}

// ---------------------------------------------------------------------------
// GEMM core (R1-proven): 128x128 tile, BK=32, double-buffered LDS with
// counted-vmcnt pipeline: issue next-step stage -> s_waitcnt vmcnt(4)
// (prefetch stays in flight across the barrier) -> s_barrier -> ds_read ->
// lgkmcnt(0) -> s_barrier (buffer-reuse guard) -> 16x MFMA.
// LDS bank swizzle: chunk position c of row r holds global chunk c^((r>>1)&3),
// realized by permuting the *source* address (verified: 0 bank conflicts).
// ---------------------------------------------------------------------------
__device__ __forceinline__ void gemm_core(const __hip_bfloat16* __restrict__ A,
                                          const __hip_bfloat16* __restrict__ Bt,
                                          int row_base, int col_base,
                                          f32x4 acc[4][4]) {
    __shared__ __hip_bfloat16 As[2][128 * 32];
    __shared__ __hip_bfloat16 Bs[2][128 * 32];

    const int tid = threadIdx.x;
    const int lane = tid & 63;
    const int wave = tid >> 6;
    const int wm = (wave >> 1) * 64;
    const int wn = (wave & 1) * 64;
    const int p = col_base >> 9;
    const int ebase = col_base & (D_BLK - 1);

    // staging: thread tid fills LDS row ar=tid>>2, chunk position c4=tid&3;
    // it must FETCH global chunk q4 = c4 ^ ((ar>>1)&3) = c4 ^ ((tid>>3)&3)
    const int ar = tid >> 2;
    const int c4 = tid & 3;
    const int kq8 = (c4 ^ ((tid >> 3) & 3)) * 8;   // fetched k-offset (elements)
    const int dst_off = ar * 32 + c4 * 8;          // == tid*8 elements = lane*16B

    const __hip_bfloat16* a_src0 = A + (size_t)(row_base + ar) * N_COLS + p * D_BLK + kq8;
    const __hip_bfloat16* a_src1 = a_src0 + (size_t)64 * N_COLS;
    const __hip_bfloat16* b_src0 = Bt + (size_t)(p * D_BLK + ebase + ar) * D_BLK + kq8;
    const __hip_bfloat16* b_src1 = b_src0 + (size_t)64 * D_BLK;

    // fragment read: lane wants row R=...+fm, k-chunk kq=lane>>4; its LDS chunk
    // position is kq ^ ((R>>1)&3) = kq ^ ((fm>>1)&3)
    const int fm = lane & 15;
    const int fkoff = ((lane >> 4) ^ ((fm >> 1) & 3)) * 8;

    for (int i = 0; i < 4; i++)
        for (int j = 0; j < 4; j++)
            acc[i][j] = (f32x4){0.0f, 0.0f, 0.0f, 0.0f};

    // prologue: stage K-step 0 into buffer 0 (4 loads in flight)
    async_ld16(a_src0, &As[0][dst_off]);
    async_ld16(a_src1, &As[0][dst_off + 64 * 32]);
    async_ld16(b_src0, &Bs[0][dst_off]);
    async_ld16(b_src1, &Bs[0][dst_off + 64 * 32]);

    int cur = 0;
    for (int k0 = 0; k0 < D_BLK; k0 += 32) {
        if (k0 + 32 < D_BLK) {
            // issue next-step stage into the other buffer (4 more loads)
            __hip_bfloat16* ad = &As[cur ^ 1][dst_off];
            __hip_bfloat16* bd = &Bs[cur ^ 1][dst_off];
            async_ld16(a_src0 + 32, ad);
            async_ld16(a_src1 + 32, ad + 64 * 32);
            async_ld16(b_src0 + 32, bd);
            async_ld16(b_src1 + 32, bd + 64 * 32);
            a_src0 += 32; a_src1 += 32; b_src0 += 32; b_src1 += 32;
            // wait only for the CURRENT buffer's 4 loads; prefetch stays in flight
            asm volatile("s_waitcnt vmcnt(4)" ::: "memory");
        } else {
            asm volatile("s_waitcnt vmcnt(0)" ::: "memory");
        }
        __builtin_amdgcn_s_barrier();          // all waves: cur buffer ready
        asm volatile("" ::: "memory");         // no LDS reads hoist above barrier

        bf16x8 af[4], bfr[4];
        const __hip_bfloat16* Asc = &As[cur][0];
        const __hip_bfloat16* Bsc = &Bs[cur][0];
#pragma unroll
        for (int i = 0; i < 4; i++)
            af[i] = *(const bf16x8*)&Asc[(wm + i * 16 + fm) * 32 + fkoff];
#pragma unroll
        for (int j = 0; j < 4; j++)
            bfr[j] = *(const bf16x8*)&Bsc[(wn + j * 16 + fm) * 32 + fkoff];
        // drain ds_reads, then fence (rule #18) so nothing slides above the wait
        asm volatile("s_waitcnt lgkmcnt(0)" ::: "memory");
        __builtin_amdgcn_sched_barrier(0);
        __builtin_amdgcn_s_barrier();          // reads done -> buffer may be overwritten
        asm volatile("" ::: "memory");

#pragma unroll
        for (int i = 0; i < 4; i++)
#pragma unroll
            for (int j = 0; j < 4; j++)
                acc[i][j] = __builtin_amdgcn_mfma_f32_16x16x32_bf16(
                    af[i], bfr[j], acc[i][j], 0, 0, 0);
        cur ^= 1;
    }
}

// ---------------------------------------------------------------------------
// GEMM1: h = x @ W1 + bias1 (bf16 out), plus per-column sum / sumsq atomics
// __launch_bounds__(256,4): cap unified regs at 128/wave -> 4 resident
// blocks/CU (was 3 at 152 regs). Budget: 64 acc (AGPR) + 32 frag + ~25 misc.
// ---------------------------------------------------------------------------
__global__ __launch_bounds__(256, 4) void gemm1_k(const __hip_bfloat16* __restrict__ xb,
                                                  const __hip_bfloat16* __restrict__ w1t,
                                                  const float* __restrict__ bias1,
                                                  __hip_bfloat16* __restrict__ h,
                                                  float* __restrict__ sum,
                                                  float* __restrict__ sumsq) {
    int row_base, col_base;
    decode_tile(blockIdx.x, row_base, col_base);

    f32x4 acc[4][4];
    gemm_core(xb, w1t, row_base, col_base, acc);

    const int tid = threadIdx.x;
    const int lane = tid & 63;
    const int wave = tid >> 6;
    const int wm = (wave >> 1) * 64;
    const int wn = (wave & 1) * 64;
    const int cr = (lane >> 4) * 4;   // C/D: row = quad*4 + reg
    const int cc = lane & 15;         // C/D: col = lane&15

#pragma unroll
    for (int j = 0; j < 4; j++) {
        const int col = col_base + wn + j * 16 + cc;
        const float b1 = bias1[col];
        float s = 0.0f, sq = 0.0f;
#pragma unroll
        for (int i = 0; i < 4; i++) {
            const int row0 = row_base + wm + i * 16 + cr;
#pragma unroll
            for (int r = 0; r < 4; r++) {
                float v = acc[i][j][r] + b1;
                h[(size_t)(row0 + r) * N_COLS + col] = __float2bfloat16(v);
                s += v;
                sq += v * v;
            }
        }
        s  += __shfl_xor(s, 16);  s  += __shfl_xor(s, 32);
        sq += __shfl_xor(sq, 16); sq += __shfl_xor(sq, 32);
        if (lane < 16) {
            atomicAdd(&sum[col], s);
            atomicAdd(&sumsq[col], sq);
        }
    }
}

// ---------------------------------------------------------------------------
// GEMM2: o3 = h_bf16 @ W2' + bias2' + x ; out = (g + sig(be*o3)*(1-g)) * o3
// ---------------------------------------------------------------------------
__global__ __launch_bounds__(256, 4) void gemm2_k(const __hip_bfloat16* __restrict__ h,
                                                  const __hip_bfloat16* __restrict__ w2t,
                                                  const float* __restrict__ bias2p,
                                                  const __hip_bfloat16* __restrict__ xb,
                                                  const float* __restrict__ gamma3,
                                                  const float* __restrict__ beta3,
                                                  float* __restrict__ out) {
    int row_base, col_base;
    decode_tile(blockIdx.x, row_base, col_base);

    f32x4 acc[4][4];
    gemm_core(h, w2t, row_base, col_base, acc);

    const int tid = threadIdx.x;
    const int lane = tid & 63;
    const int wave = tid >> 6;
    const int wm = (wave >> 1) * 64;
    const int wn = (wave & 1) * 64;
    const int cr = (lane >> 4) * 4;
    const int cc = lane & 15;

#pragma unroll
    for (int j = 0; j < 4; j++) {
        const int col = col_base + wn + j * 16 + cc;
        const float bb = bias2p[col];
        const float g  = gamma3[col];
        const float be = beta3[col];
#pragma unroll
        for (int i = 0; i < 4; i++) {
            const int row0 = row_base + wm + i * 16 + cr;
#pragma unroll
            for (int r = 0; r < 4; r++) {
                const size_t idx = (size_t)(row0 + r) * N_COLS + col;
                float o3 = acc[i][j][r] + bb + __bfloat162float(xb[idx]);
                float sg = __fdividef(1.0f, 1.0f + __expf(-be * o3));
                out[idx] = (g + sg * (1.0f - g)) * o3;
            }
        }
    }
}

// ---------------------------------------------------------------------------
extern "C" void kernel_launch(void* const* d_in, const int* in_sizes, int n_in,
                              void* d_out, int out_size, void* d_ws, size_t ws_size,
                              hipStream_t stream) {
    const float* x     = (const float*)d_in[0];
    const float* W1    = (const float*)d_in[1];
    const float* bias1 = (const float*)d_in[2];
    const float* W2    = (const float*)d_in[3];
    const float* bias2 = (const float*)d_in[4];
    const float* bnw   = (const float*)d_in[5];
    const float* bnb   = (const float*)d_in[6];
    const float* gam3  = (const float*)d_in[7];
    const float* bet3  = (const float*)d_in[8];
    float* out = (float*)d_out;

    // workspace layout
    char* ws = (char*)d_ws;
    const size_t XB_BYTES = (size_t)B_ROWS * N_COLS * 2;        // 64 MiB
    const size_t H_BYTES  = (size_t)B_ROWS * N_COLS * 2;        // 64 MiB
    const size_t WT_BYTES = (size_t)P_BLK * D_BLK * D_BLK * 2;  // 4 MiB
    const size_t V_BYTES  = (size_t)N_COLS * 4;                 // 16 KiB

    __hip_bfloat16* xb   = (__hip_bfloat16*)(ws);
    __hip_bfloat16* hbuf = (__hip_bfloat16*)(ws + XB_BYTES);
    __hip_bfloat16* w1t  = (__hip_bfloat16*)(ws + XB_BYTES + H_BYTES);
    __hip_bfloat16* w2t  = (__hip_bfloat16*)(ws + XB_BYTES + H_BYTES + WT_BYTES);
    float* sums  = (float*)(ws + XB_BYTES + H_BYTES + 2 * WT_BYTES);
    float* sumsq = sums + N_COLS;
    float* b2p   = sums + 2 * N_COLS;   // zeroed: mid_k accumulates via atomics

    (void)in_sizes; (void)n_in; (void)out_size; (void)ws_size;

    // zero stats accumulators + bias2' (ws is poisoned before every call)
    hipMemsetAsync(sums, 0, 3 * V_BYTES, stream);

    // x -> bf16  fused with  W1 -> bf16 transposed [p,e,d]
    prep_k<<<dim3(16384 + 2048), dim3(256), 0, stream>>>(x, xb, W1, w1t);
    // GEMM1 + bias + stats
    gemm1_k<<<dim3((B_ROWS / 128) * (N_COLS / 128)), dim3(256), 0, stream>>>(
        xb, w1t, bias1, hbuf, sums, sumsq);
    // W2' (scale from stats, inline finalize) + bias2' (inline c)
    mid_k<<<dim3(2048 + 128), dim3(256), 0, stream>>>(
        W2, sums, sumsq, bnw, bnb, bias2, w2t, b2p);
    // GEMM2 + residual + gate
    gemm2_k<<<dim3((B_ROWS / 128) * (N_COLS / 128)), dim3(256), 0, stream>>>(
        hbuf, w2t, b2p, xb, gam3, bet3, out);
}

// Round 4
// 404.030 us; speedup vs baseline: 1.0522x; 1.0235x over previous
//
#include <hip/hip_runtime.h>
#include <hip/hip_bf16.h>
#include <cstdint>
#include <cstddef>

#define B_ROWS 8192
#define N_COLS 4096
#define P_BLK 8
#define D_BLK 512
#define EPSV 1e-5f

typedef __bf16 bf16x8 __attribute__((ext_vector_type(8)));
typedef float f32x4 __attribute__((ext_vector_type(4)));

// ---------------------------------------------------------------------------
// async 16B global -> LDS (HW: LDS dst = wave-uniform base + lane*16)
// ---------------------------------------------------------------------------
__device__ __forceinline__ void async_ld16(const void* g, void* l) {
    __builtin_amdgcn_global_load_lds(
        (const __attribute__((address_space(1))) void*)g,
        (__attribute__((address_space(3))) void*)l,
        16, 0, 0);
}

// ---------------------------------------------------------------------------
// block swizzle: flat id n -> (row_tile, col_tile) such that the 4 blocks
// sharing one A-slab (same row-strip, same diagonal block p) are n, n+8,
// n+16, n+24 -> same XCD under %8 round-robin.
// ---------------------------------------------------------------------------
__device__ __forceinline__ void decode_tile(int n, int& row_base, int& col_base) {
    const int row_tile = n >> 5;
    const int col_tile = ((n & 7) << 2) | ((n >> 3) & 3);
    row_base = row_tile * 128;
    col_base = col_tile * 128;
}

// ---------------------------------------------------------------------------
// x fp32 -> bf16 (blocks [0,16384)) fused with W1 transpose (blocks >= 16384)
// ---------------------------------------------------------------------------
__global__ __launch_bounds__(256) void prep_k(const float* __restrict__ x,
                                              __hip_bfloat16* __restrict__ xb,
                                              const float* __restrict__ W1,
                                              __hip_bfloat16* __restrict__ w1t) {
    __shared__ float tl[32][33];
    if (blockIdx.x < 16384) {
        size_t i = ((size_t)blockIdx.x * 256 + threadIdx.x) * 8;
        float4 v0 = *(const float4*)(x + i);
        float4 v1 = *(const float4*)(x + i + 4);
        union { __hip_bfloat16 h[8]; uint4 u; } r;
        r.h[0] = __float2bfloat16(v0.x); r.h[1] = __float2bfloat16(v0.y);
        r.h[2] = __float2bfloat16(v0.z); r.h[3] = __float2bfloat16(v0.w);
        r.h[4] = __float2bfloat16(v1.x); r.h[5] = __float2bfloat16(v1.y);
        r.h[6] = __float2bfloat16(v1.z); r.h[7] = __float2bfloat16(v1.w);
        *(uint4*)(xb + i) = r.u;
        return;
    }
    const int n = blockIdx.x - 16384;            // 0..2047
    const int p = n >> 8;
    const int rem = n & 255;
    const int d0 = (rem & 15) * 32, e0 = (rem >> 4) * 32;
    const int tx = threadIdx.x & 31, ty = threadIdx.x >> 5;
    const float* Wp = W1 + (size_t)p * D_BLK * D_BLK;
    for (int j = 0; j < 32; j += 8) {
        int d = d0 + ty + j;
        tl[ty + j][tx] = Wp[(size_t)d * D_BLK + e0 + tx];
    }
    __syncthreads();
    __hip_bfloat16* Wtp = w1t + (size_t)p * D_BLK * D_BLK;
    for (int j = 0; j < 32; j += 8) {
        int e = e0 + ty + j;
        Wtp[(size_t)e * D_BLK + d0 + tx] = __float2bfloat16(tl[tx][ty + j]);
    }
}

// ---------------------------------------------------------------------------
// mid kernel: blocks [0,2048): W2' = a[d]*W2 transposed bf16 (a from stats);
//             blocks [2048,2176): bias2'[col] += bias2 + sum_d c[d]*W2[p,d,e]
// finalize_k folded in: a,c computed inline from sums/sumsq.
// ---------------------------------------------------------------------------
__global__ __launch_bounds__(256) void mid_k(const float* __restrict__ W2,
                                             const float* __restrict__ sums,
                                             const float* __restrict__ sumsq,
                                             const float* __restrict__ bnw,
                                             const float* __restrict__ bnb,
                                             const float* __restrict__ bias2,
                                             __hip_bfloat16* __restrict__ w2t,
                                             float* __restrict__ b2p) {
    __shared__ float tl[32][33];
    __shared__ float as_[32];
    const float invB = 1.0f / B_ROWS;
    if (blockIdx.x < 2048) {
        const int n = blockIdx.x;
        const int p = n >> 8;
        const int rem = n & 255;
        const int d0 = (rem & 15) * 32, e0 = (rem >> 4) * 32;
        const int tx = threadIdx.x & 31, ty = threadIdx.x >> 5;
        if (threadIdx.x < 32) {
            int idx = p * D_BLK + d0 + threadIdx.x;
            float m = sums[idx] * invB;
            float var = sumsq[idx] * invB - m * m;
            as_[threadIdx.x] = bnw[idx] * rsqrtf(var + EPSV);
        }
        __syncthreads();
        const float* Wp = W2 + (size_t)p * D_BLK * D_BLK;
        for (int j = 0; j < 32; j += 8) {
            int d = d0 + ty + j;
            tl[ty + j][tx] = Wp[(size_t)d * D_BLK + e0 + tx] * as_[ty + j];
        }
        __syncthreads();
        __hip_bfloat16* Wtp = w2t + (size_t)p * D_BLK * D_BLK;
        for (int j = 0; j < 32; j += 8) {
            int e = e0 + ty + j;
            Wtp[(size_t)e * D_BLK + d0 + tx] = __float2bfloat16(tl[tx][ty + j]);
        }
        return;
    }
    const int n2 = blockIdx.x - 2048;            // 0..127
    const int colblk = n2 & 15, chunk = n2 >> 4;
    const int col = colblk * 256 + threadIdx.x;
    const int p = col >> 9;
    const int e = col & (D_BLK - 1);
    const int d0 = chunk * 64;
    float acc = (chunk == 0) ? bias2[col] : 0.0f;
    for (int d = 0; d < 64; d++) {
        int idx = p * D_BLK + d0 + d;
        float m = sums[idx] * invB;
        float var = sumsq[idx] * invB - m * m;
        float ai = bnw[idx] * rsqrtf(var + EPSV);
        float ci = bnb[idx] - m * ai;
        acc += ci * W2[((size_t)p * D_BLK + d0 + d) * D_BLK + e];
    }
    atomicAdd(&b2p[col], acc);
}

// ---------------------------------------------------------------------------
// GEMM core: 128x128 tile, BK=32, TRIPLE-buffered LDS, prefetch distance 2,
// ONE barrier per K-step.
//
// Correctness argument (single barrier):
//  - RAW (stage->ds_read): loop-top vmcnt(4) retires S(k) (oldest 4 loads;
//    S(k+1)'s 4 stay in flight), so buf k%3 is complete before the barrier.
//  - WAR (ds_read->stage): stage S(k+2) writes buf (k+2)%3, last read at
//    step k-1. Every wave's ds_reads(k-1) retire before its MFMAs(k-1)
//    (lgkmcnt(0) dep), which precede its arrival at barrier(k); the stage is
//    issued AFTER barrier(k), so no wave can still be reading that buffer.
//  Cover distance for S(k): issued after barrier(k-2), waited at top of k
//  = TWO full phases (ds_read+MFMA x2) > ~900cy HBM-miss latency. The old
//  2-barrier schedule covered only one phase -> stalled every K-step.
//
// LDS bank swizzle unchanged: chunk position c of row r holds global chunk
// c^((r>>1)&3), realized by permuting the *source* address (verified: 0
// bank conflicts). LDS = 3 x 16 KB = 48 KB -> 3 blocks/CU (same residency
// as R1; R3 showed more residency thrashes L2: FETCH +54%).
// ---------------------------------------------------------------------------
__device__ __forceinline__ void gemm_core(const __hip_bfloat16* __restrict__ A,
                                          const __hip_bfloat16* __restrict__ Bt,
                                          int row_base, int col_base,
                                          f32x4 acc[4][4]) {
    __shared__ __hip_bfloat16 As[3][128 * 32];
    __shared__ __hip_bfloat16 Bs[3][128 * 32];

    const int tid = threadIdx.x;
    const int lane = tid & 63;
    const int wave = tid >> 6;
    const int wm = (wave >> 1) * 64;
    const int wn = (wave & 1) * 64;
    const int p = col_base >> 9;
    const int ebase = col_base & (D_BLK - 1);

    // staging: thread tid fills LDS row ar=tid>>2, chunk position c4=tid&3;
    // it must FETCH global chunk q4 = c4 ^ ((ar>>1)&3) = c4 ^ ((tid>>3)&3)
    const int ar = tid >> 2;
    const int c4 = tid & 3;
    const int kq8 = (c4 ^ ((tid >> 3) & 3)) * 8;   // fetched k-offset (elements)
    const int dst_off = ar * 32 + c4 * 8;          // == tid*8 elements = lane*16B

    const __hip_bfloat16* a_src0 = A + (size_t)(row_base + ar) * N_COLS + p * D_BLK + kq8;
    const __hip_bfloat16* a_src1 = a_src0 + (size_t)64 * N_COLS;
    const __hip_bfloat16* b_src0 = Bt + (size_t)(p * D_BLK + ebase + ar) * D_BLK + kq8;
    const __hip_bfloat16* b_src1 = b_src0 + (size_t)64 * D_BLK;

    // fragment read: lane wants row R=...+fm, k-chunk kq=lane>>4; its LDS chunk
    // position is kq ^ ((R>>1)&3) = kq ^ ((fm>>1)&3)
    const int fm = lane & 15;
    const int fkoff = ((lane >> 4) ^ ((fm >> 1) & 3)) * 8;

#pragma unroll
    for (int i = 0; i < 4; i++)
#pragma unroll
        for (int j = 0; j < 4; j++)
            acc[i][j] = (f32x4){0.0f, 0.0f, 0.0f, 0.0f};

    // prologue: stage S0 (buf0) and S1 (buf1) — 8 loads in flight
#pragma unroll
    for (int s = 0; s < 2; s++) {
        __hip_bfloat16* ad = &As[s][dst_off];
        __hip_bfloat16* bd = &Bs[s][dst_off];
        async_ld16(a_src0, ad);
        async_ld16(a_src1, ad + 64 * 32);
        async_ld16(b_src0, bd);
        async_ld16(b_src1, bd + 64 * 32);
        a_src0 += 32; a_src1 += 32; b_src0 += 32; b_src1 += 32;
    }

#pragma unroll
    for (int k = 0; k < 16; ++k) {
        const int rb = k % 3;            // read buffer (static after unroll)
        const int sb = (k + 2) % 3;      // stage buffer

        // retire S(k)'s 4 loads; S(k+1)'s 4 stay in flight (except tail)
        if (k < 15) {
            asm volatile("s_waitcnt vmcnt(4)" ::: "memory");
        } else {
            asm volatile("s_waitcnt vmcnt(0)" ::: "memory");
        }
        __builtin_amdgcn_s_barrier();        // buf rb ready for ALL waves;
        asm volatile("" ::: "memory");       // also: all reads of buf sb done

        if (k < 14) {                        // stage S(k+2) into buf sb
            __hip_bfloat16* ad = &As[sb][dst_off];
            __hip_bfloat16* bd = &Bs[sb][dst_off];
            async_ld16(a_src0, ad);
            async_ld16(a_src1, ad + 64 * 32);
            async_ld16(b_src0, bd);
            async_ld16(b_src1, bd + 64 * 32);
            a_src0 += 32; a_src1 += 32; b_src0 += 32; b_src1 += 32;
        }

        bf16x8 af[4], bfr[4];
        const __hip_bfloat16* Asc = &As[rb][0];
        const __hip_bfloat16* Bsc = &Bs[rb][0];
#pragma unroll
        for (int i = 0; i < 4; i++)
            af[i] = *(const bf16x8*)&Asc[(wm + i * 16 + fm) * 32 + fkoff];
#pragma unroll
        for (int j = 0; j < 4; j++)
            bfr[j] = *(const bf16x8*)&Bsc[(wn + j * 16 + fm) * 32 + fkoff];
        // drain ds_reads; fence (rule #18) so MFMAs can't slide above the wait
        asm volatile("s_waitcnt lgkmcnt(0)" ::: "memory");
        __builtin_amdgcn_sched_barrier(0);

#pragma unroll
        for (int i = 0; i < 4; i++)
#pragma unroll
            for (int j = 0; j < 4; j++)
                acc[i][j] = __builtin_amdgcn_mfma_f32_16x16x32_bf16(
                    af[i], bfr[j], acc[i][j], 0, 0, 0);
    }
}

// ---------------------------------------------------------------------------
// GEMM1: h = x @ W1 + bias1 (bf16 out), plus per-column sum / sumsq atomics
// Plain launch bounds: R3 proved forcing 4 blocks/CU thrashes L2 (+54% FETCH)
// ---------------------------------------------------------------------------
__global__ __launch_bounds__(256) void gemm1_k(const __hip_bfloat16* __restrict__ xb,
                                               const __hip_bfloat16* __restrict__ w1t,
                                               const float* __restrict__ bias1,
                                               __hip_bfloat16* __restrict__ h,
                                               float* __restrict__ sum,
                                               float* __restrict__ sumsq) {
    int row_base, col_base;
    decode_tile(blockIdx.x, row_base, col_base);

    f32x4 acc[4][4];
    gemm_core(xb, w1t, row_base, col_base, acc);

    const int tid = threadIdx.x;
    const int lane = tid & 63;
    const int wave = tid >> 6;
    const int wm = (wave >> 1) * 64;
    const int wn = (wave & 1) * 64;
    const int cr = (lane >> 4) * 4;   // C/D: row = quad*4 + reg
    const int cc = lane & 15;         // C/D: col = lane&15

#pragma unroll
    for (int j = 0; j < 4; j++) {
        const int col = col_base + wn + j * 16 + cc;
        const float b1 = bias1[col];
        float s = 0.0f, sq = 0.0f;
#pragma unroll
        for (int i = 0; i < 4; i++) {
            const int row0 = row_base + wm + i * 16 + cr;
#pragma unroll
            for (int r = 0; r < 4; r++) {
                float v = acc[i][j][r] + b1;
                h[(size_t)(row0 + r) * N_COLS + col] = __float2bfloat16(v);
                s += v;
                sq += v * v;
            }
        }
        s  += __shfl_xor(s, 16);  s  += __shfl_xor(s, 32);
        sq += __shfl_xor(sq, 16); sq += __shfl_xor(sq, 32);
        if (lane < 16) {
            atomicAdd(&sum[col], s);
            atomicAdd(&sumsq[col], sq);
        }
    }
}

// ---------------------------------------------------------------------------
// GEMM2: o3 = h_bf16 @ W2' + bias2' + x ; out = (g + sig(be*o3)*(1-g)) * o3
// ---------------------------------------------------------------------------
__global__ __launch_bounds__(256) void gemm2_k(const __hip_bfloat16* __restrict__ h,
                                               const __hip_bfloat16* __restrict__ w2t,
                                               const float* __restrict__ bias2p,
                                               const __hip_bfloat16* __restrict__ xb,
                                               const float* __restrict__ gamma3,
                                               const float* __restrict__ beta3,
                                               float* __restrict__ out) {
    int row_base, col_base;
    decode_tile(blockIdx.x, row_base, col_base);

    f32x4 acc[4][4];
    gemm_core(h, w2t, row_base, col_base, acc);

    const int tid = threadIdx.x;
    const int lane = tid & 63;
    const int wave = tid >> 6;
    const int wm = (wave >> 1) * 64;
    const int wn = (wave & 1) * 64;
    const int cr = (lane >> 4) * 4;
    const int cc = lane & 15;

#pragma unroll
    for (int j = 0; j < 4; j++) {
        const int col = col_base + wn + j * 16 + cc;
        const float bb = bias2p[col];
        const float g  = gamma3[col];
        const float be = beta3[col];
#pragma unroll
        for (int i = 0; i < 4; i++) {
            const int row0 = row_base + wm + i * 16 + cr;
#pragma unroll
            for (int r = 0; r < 4; r++) {
                const size_t idx = (size_t)(row0 + r) * N_COLS + col;
                float o3 = acc[i][j][r] + bb + __bfloat162float(xb[idx]);
                float sg = __fdividef(1.0f, 1.0f + __expf(-be * o3));
                out[idx] = (g + sg * (1.0f - g)) * o3;
            }
        }
    }
}

// ---------------------------------------------------------------------------
extern "C" void kernel_launch(void* const* d_in, const int* in_sizes, int n_in,
                              void* d_out, int out_size, void* d_ws, size_t ws_size,
                              hipStream_t stream) {
    const float* x     = (const float*)d_in[0];
    const float* W1    = (const float*)d_in[1];
    const float* bias1 = (const float*)d_in[2];
    const float* W2    = (const float*)d_in[3];
    const float* bias2 = (const float*)d_in[4];
    const float* bnw   = (const float*)d_in[5];
    const float* bnb   = (const float*)d_in[6];
    const float* gam3  = (const float*)d_in[7];
    const float* bet3  = (const float*)d_in[8];
    float* out = (float*)d_out;

    // workspace layout
    char* ws = (char*)d_ws;
    const size_t XB_BYTES = (size_t)B_ROWS * N_COLS * 2;        // 64 MiB
    const size_t H_BYTES  = (size_t)B_ROWS * N_COLS * 2;        // 64 MiB
    const size_t WT_BYTES = (size_t)P_BLK * D_BLK * D_BLK * 2;  // 4 MiB
    const size_t V_BYTES  = (size_t)N_COLS * 4;                 // 16 KiB

    __hip_bfloat16* xb   = (__hip_bfloat16*)(ws);
    __hip_bfloat16* hbuf = (__hip_bfloat16*)(ws + XB_BYTES);
    __hip_bfloat16* w1t  = (__hip_bfloat16*)(ws + XB_BYTES + H_BYTES);
    __hip_bfloat16* w2t  = (__hip_bfloat16*)(ws + XB_BYTES + H_BYTES + WT_BYTES);
    float* sums  = (float*)(ws + XB_BYTES + H_BYTES + 2 * WT_BYTES);
    float* sumsq = sums + N_COLS;
    float* b2p   = sums + 2 * N_COLS;   // zeroed: mid_k accumulates via atomics

    (void)in_sizes; (void)n_in; (void)out_size; (void)ws_size;

    // zero stats accumulators + bias2' (ws is poisoned before every call)
    hipMemsetAsync(sums, 0, 3 * V_BYTES, stream);

    // x -> bf16  fused with  W1 -> bf16 transposed [p,e,d]
    prep_k<<<dim3(16384 + 2048), dim3(256), 0, stream>>>(x, xb, W1, w1t);
    // GEMM1 + bias + stats
    gemm1_k<<<dim3((B_ROWS / 128) * (N_COLS / 128)), dim3(256), 0, stream>>>(
        xb, w1t, bias1, hbuf, sums, sumsq);
    // W2' (scale from stats, inline finalize) + bias2' (inline c)
    mid_k<<<dim3(2048 + 128), dim3(256), 0, stream>>>(
        W2, sums, sumsq, bnw, bnb, bias2, w2t, b2p);
    // GEMM2 + residual + gate
    gemm2_k<<<dim3((B_ROWS / 128) * (N_COLS / 128)), dim3(256), 0, stream>>>(
        hbuf, w2t, b2p, xb, gam3, bet3, out);
}